// Round 10
// baseline (63.031 us; speedup 1.0000x reference)
//
#include <hip/hip_runtime.h>

// FractalEmbedding: cs[M,2] -> 8 Julia iters -> feats[M,16]
//                   out[M,D] = feats @ W^T * scale   (W is [D,16] row-major)
// M = 32768, D = 2048, fp32 out = 256 MiB -> write-BW-bound (fill ~7.06 TB/s).
//
// R10: R9 byte-identical EXCEPT the two row stores are nontemporal (single
// variable A/B). Theory: output == L3 size, rewritten each replay with zero
// reuse -> cached writes fight dirty-line ownership/eviction of last replay's
// copies; nt streams past L2/L3 allocate. R3's nt removal was confounded
// (bundled with pk-fma, worse structure) -- this isolates it on the best one.

#define STEPS 8
#define KF 16
#define DDIM 2048
#define BLOCK 256
#define CPT 8                 // columns per thread: two dense 4-col groups
#define ROWS_PER_BLK 64

typedef float f32x2 __attribute__((ext_vector_type(2)));
typedef float f32x4 __attribute__((ext_vector_type(4)));

__global__ __launch_bounds__(BLOCK, 2) void fractal_embed_kernel(
    const float* __restrict__ cs,     // [M,2] interleaved (cr, ci)
    const float* __restrict__ W,      // [D,16] row-major
    const float* __restrict__ scale,  // [1]
    float* __restrict__ out)          // [M,D]
{
    const int tid  = threadIdx.x;
    const int row0 = blockIdx.x * ROWS_PER_BLK;
    const int ca   = tid * 4;          // cols    0..1023 across the block
    const int cb   = 1024 + tid * 4;   // cols 1024..2047 across the block

    // Stage this block's 64 (cr,ci) pairs into LDS: one coalesced 512 B load.
    __shared__ float s_cs[2 * ROWS_PER_BLK];
    if (tid < 2 * ROWS_PER_BLK)
        s_cs[tid] = cs[(size_t)row0 * 2 + tid];

    const float s = scale[0];

    // W rows for this thread's 8 columns, scale folded in. 128 VGPRs.
    f32x2 w2[CPT][KF / 2];
#pragma unroll
    for (int r = 0; r < CPT; ++r) {
        const int d = (r < 4) ? (ca + r) : (cb + (r - 4));
        const f32x2* wp = reinterpret_cast<const f32x2*>(W + (size_t)d * KF);
#pragma unroll
        for (int q = 0; q < KF / 2; ++q) {
            f32x2 v = wp[q];
            v.x *= s; v.y *= s;
            w2[r][q] = v;
        }
    }
    __syncthreads();

#pragma unroll 4
    for (int rr = 0; rr < ROWS_PER_BLK; ++rr) {
        const int row = row0 + rr;
        const float cr = s_cs[2 * rr];       // wave-uniform broadcast reads
        const float ci = s_cs[2 * rr + 1];

        // Julia iteration z <- z^2 + c from z=0; f2[st] = (zr, zi).
        f32x2 f2[STEPS];
        float zr = 0.0f, zi = 0.0f;
#pragma unroll
        for (int st = 0; st < STEPS; ++st) {
            const float nzr = fmaf(zr, zr, fmaf(-zi, zi, cr));
            const float nzi = fmaf(zr + zr, zi, ci);
            zr = nzr; zi = nzi;
            f2[st].x = zr;
            f2[st].y = zi;
        }

        // 8 dot products (length 16) via pk-fma against register W.
        f32x4 oa, ob;
#pragma unroll
        for (int r = 0; r < CPT; ++r) {
            f32x2 a2 = {0.0f, 0.0f};
#pragma unroll
            for (int q = 0; q < KF / 2; ++q)
                a2 = __builtin_elementwise_fma(f2[q], w2[r][q], a2);
            const float v = a2.x + a2.y;
            if (r < 4) oa[r] = v;
            else       ob[r - 4] = v;
        }

        // Two dense 1 KB-per-wave NONTEMPORAL stores; slab walks row-major.
        float* rowp = out + (size_t)row * DDIM;
        __builtin_nontemporal_store(oa, reinterpret_cast<f32x4*>(rowp + ca));
        __builtin_nontemporal_store(ob, reinterpret_cast<f32x4*>(rowp + cb));
    }
}

extern "C" void kernel_launch(void* const* d_in, const int* in_sizes, int n_in,
                              void* d_out, int out_size, void* d_ws, size_t ws_size,
                              hipStream_t stream) {
    // d_in[0] = token_ids (int64, unused — cs precomputed host-side)
    // d_in[1] = cs [B,L,2] f32; d_in[2] = W [D,16] f32; d_in[3] = scale [1] f32
    const float* cs    = (const float*)d_in[1];
    const float* W     = (const float*)d_in[2];
    const float* scale = (const float*)d_in[3];
    float* out         = (float*)d_out;

    const int M = in_sizes[0];                 // B*L = 32768 rows
    const int grid = M / ROWS_PER_BLK;         // 512 blocks: one generation
    fractal_embed_kernel<<<grid, BLOCK, 0, stream>>>(cs, W, scale, out);
}

// Round 11
// 52.095 us; speedup vs baseline: 1.2099x; 1.2099x over previous
//
#include <hip/hip_runtime.h>

// FractalEmbedding: cs[M,2] -> 8 Julia iters -> feats[M,16]
//                   out[M,D] = feats @ W^T * scale   (W is [D,16] row-major)
// M = 32768, D = 2048, fp32 out = 256 MiB -> write-BW-bound.
//
// FINAL (= R9, measured 52.06 us = 5.16 TB/s effective): one co-resident
// block generation (512 blocks x 256 thr, 2 blocks/CU), each block writing a
// contiguous 512 KB slab row-major with dense 1 KB wave stores; cs staged in
// LDS; W in registers with scale folded; pk-fma dot; unroll-4 row loop;
// CACHED stores (nt-store A/B regressed 52->63 us: L2/L3 write absorption
// is worth ~11 us on this exactly-L3-sized output).
//
// Sweep history: compute structure (scalar/pk-fma/MFMA) null; store pattern
// (panels/slab/sweep) slab best; generations 2->1 won -5us; occupancy x2
// regressed; unroll depth x2 null; nt regressed. Residual ~14us over the
// 38us payload floor is payload-independent (kernel-boundary cache
// maintenance + ramp/drain), unmovable by any tested axis => roofline.

#define STEPS 8
#define KF 16
#define DDIM 2048
#define BLOCK 256
#define CPT 8                 // columns per thread: two dense 4-col groups
#define ROWS_PER_BLK 64

typedef float f32x2 __attribute__((ext_vector_type(2)));
typedef float f32x4 __attribute__((ext_vector_type(4)));

__global__ __launch_bounds__(BLOCK, 2) void fractal_embed_kernel(
    const float* __restrict__ cs,     // [M,2] interleaved (cr, ci)
    const float* __restrict__ W,      // [D,16] row-major
    const float* __restrict__ scale,  // [1]
    float* __restrict__ out)          // [M,D]
{
    const int tid  = threadIdx.x;
    const int row0 = blockIdx.x * ROWS_PER_BLK;
    const int ca   = tid * 4;          // cols    0..1023 across the block
    const int cb   = 1024 + tid * 4;   // cols 1024..2047 across the block

    // Stage this block's 64 (cr,ci) pairs into LDS: one coalesced 512 B load.
    __shared__ float s_cs[2 * ROWS_PER_BLK];
    if (tid < 2 * ROWS_PER_BLK)
        s_cs[tid] = cs[(size_t)row0 * 2 + tid];

    const float s = scale[0];

    // W rows for this thread's 8 columns, scale folded in. 128 VGPRs.
    f32x2 w2[CPT][KF / 2];
#pragma unroll
    for (int r = 0; r < CPT; ++r) {
        const int d = (r < 4) ? (ca + r) : (cb + (r - 4));
        const f32x2* wp = reinterpret_cast<const f32x2*>(W + (size_t)d * KF);
#pragma unroll
        for (int q = 0; q < KF / 2; ++q) {
            f32x2 v = wp[q];
            v.x *= s; v.y *= s;
            w2[r][q] = v;
        }
    }
    __syncthreads();

#pragma unroll 4
    for (int rr = 0; rr < ROWS_PER_BLK; ++rr) {
        const int row = row0 + rr;
        const float cr = s_cs[2 * rr];       // wave-uniform broadcast reads
        const float ci = s_cs[2 * rr + 1];

        // Julia iteration z <- z^2 + c from z=0; f2[st] = (zr, zi).
        f32x2 f2[STEPS];
        float zr = 0.0f, zi = 0.0f;
#pragma unroll
        for (int st = 0; st < STEPS; ++st) {
            const float nzr = fmaf(zr, zr, fmaf(-zi, zi, cr));
            const float nzi = fmaf(zr + zr, zi, ci);
            zr = nzr; zi = nzi;
            f2[st].x = zr;
            f2[st].y = zi;
        }

        // 8 dot products (length 16) via pk-fma against register W.
        f32x4 oa, ob;
#pragma unroll
        for (int r = 0; r < CPT; ++r) {
            f32x2 a2 = {0.0f, 0.0f};
#pragma unroll
            for (int q = 0; q < KF / 2; ++q)
                a2 = __builtin_elementwise_fma(f2[q], w2[r][q], a2);
            const float v = a2.x + a2.y;
            if (r < 4) oa[r] = v;
            else       ob[r - 4] = v;
        }

        // Two dense 1 KB-per-wave stores; block walks a 512 KB slab row-major.
        float* rowp = out + (size_t)row * DDIM;
        reinterpret_cast<f32x4*>(rowp + ca)[0] = oa;
        reinterpret_cast<f32x4*>(rowp + cb)[0] = ob;
    }
}

extern "C" void kernel_launch(void* const* d_in, const int* in_sizes, int n_in,
                              void* d_out, int out_size, void* d_ws, size_t ws_size,
                              hipStream_t stream) {
    // d_in[0] = token_ids (int64, unused — cs precomputed host-side)
    // d_in[1] = cs [B,L,2] f32; d_in[2] = W [D,16] f32; d_in[3] = scale [1] f32
    const float* cs    = (const float*)d_in[1];
    const float* W     = (const float*)d_in[2];
    const float* scale = (const float*)d_in[3];
    float* out         = (float*)d_out;

    const int M = in_sizes[0];                 // B*L = 32768 rows
    const int grid = M / ROWS_PER_BLK;         // 512 blocks: one generation
    fractal_embed_kernel<<<grid, BLOCK, 0, stream>>>(cs, W, scale, out);
}